// Round 6
// baseline (275.998 us; speedup 1.0000x reference)
//
#include <hip/hip_runtime.h>
#include <stdint.h>

// Problem constants
#define BB    16
#define DIMC  512
#define CHC   256
#define REDC  64
#define LL    32          // H == W == 32
#define NTOK  (BB*LL*LL)  // 16384 tokens

typedef unsigned short u16;
typedef __attribute__((ext_vector_type(4))) float f32x4;
typedef __attribute__((ext_vector_type(8))) short bf16x8;

__device__ __forceinline__ float bf2f(u16 u){
  union { unsigned int i; float f; } v; v.i = ((unsigned int)u) << 16; return v.f;
}
__device__ __forceinline__ u16 f2bf(float f){
  union { float f; unsigned int i; } v; v.f = f;
  unsigned int r = (v.i + 0x7FFFu + ((v.i >> 16) & 1u)) >> 16;
  return (u16)r;
}

// async global->LDS, 16B per lane; LDS base must be wave-uniform.
__device__ __forceinline__ void gload16(const u16* g, u16* l) {
  __builtin_amdgcn_global_load_lds(
      (const __attribute__((address_space(1))) void*)g,
      (__attribute__((address_space(3))) void*)l, 16, 0, 0);
}

// ---------------------------------------------------------------------------
// K0: fused pre-pass. Blocks 0..511: weight transposes fp32 [K][N]->bf16 [N][K].
// Blocks 512..8703: per-(b,ch) axis means -> g[br][b][c][l].
__global__ __launch_bounds__(256) void k_pre(const float* __restrict__ s1,
    u16* __restrict__ d1, const float* __restrict__ s2, u16* __restrict__ d2,
    const float* __restrict__ x, const float* __restrict__ pe_h,
    const float* __restrict__ pe_w, float* __restrict__ g)
{
  int tid = threadIdx.x;
  if (blockIdx.x < 512) {
    __shared__ u16 t[64][65];
    int bid = blockIdx.x;
    const float* src; u16* dst; int K, N, n0, k0;
    if (bid < 256) { src = s1; dst = d1; K = 512;  N = 2048; n0 = (bid & 31) * 64; k0 = (bid >> 5) * 64; }
    else { bid -= 256; src = s2; dst = d2; K = 2048; N = 512; n0 = (bid & 7) * 64; k0 = (bid >> 3) * 64; }
    #pragma unroll
    for (int i = 0; i < 16; ++i) {
      int idx = i*256 + tid; int r = idx >> 6, c = idx & 63;
      t[r][c] = f2bf(src[(size_t)(k0 + r) * N + n0 + c]);
    }
    __syncthreads();
    #pragma unroll
    for (int i = 0; i < 16; ++i) {
      int idx = i*256 + tid; int c = idx >> 6, r = idx & 63;
      dst[(size_t)(n0 + c) * K + k0 + r] = t[r][c];
    }
    return;
  }
  // ---- means part ----
  int bc = blockIdx.x - 512;           // b*512 + ch
  int br = (bc & 511) >> 8, c = bc & 255;
  __shared__ float tt[32][33];
  const float* xp = x + (size_t)bc * 1024;
  float4 v = ((const float4*)xp)[tid];
  int h = tid >> 3, w4 = (tid & 7) * 4;
  tt[h][w4+0] = v.x; tt[h][w4+1] = v.y; tt[h][w4+2] = v.z; tt[h][w4+3] = v.w;
  __syncthreads();
  if (tid < 32) {
    float rs = 0.f;
    if (br == 0) {
      #pragma unroll
      for (int w = 0; w < 32; ++w) rs += tt[tid][w];     // mean over W (H-branch)
    } else {
      #pragma unroll
      for (int h2 = 0; h2 < 32; ++h2) rs += tt[h2][tid]; // mean over H (W-branch)
    }
    float tot = rs;
    #pragma unroll
    for (int off = 16; off >= 1; off >>= 1) tot += __shfl_xor(tot, off);
    const float* pe = (br == 0 ? pe_h : pe_w) + c*32;
    float pv = pe[tid];
    float pm = pv;
    #pragma unroll
    for (int off = 16; off >= 1; off >>= 1) pm += __shfl_xor(pm, off);
    int b = bc >> 9;
    float gv = rs * (1.f/32.f) + tot * (1.f/1024.f) + pv + pm * (1.f/32.f);
    g[((size_t)(br*BB + b)*256 + c)*32 + tid] = gv;
  }
}

// ---------------------------------------------------------------------------
// K2: generator net: conv1(256->64,k3) -> BN -> hardswish -> conv2(64->256,k3)
//     -> per-batch filter norm * fns + fnm.  One block per (branch, batch).
__global__ __launch_bounds__(256) void k_gen(
    const float* __restrict__ g, float* __restrict__ wout,
    const float* g1w_h, const float* bng_h, const float* bnb_h, const float* bnrm_h,
    const float* bnrv_h, const float* g2w_h, const float* fns_h, const float* fnm_h,
    const float* g1w_w, const float* bng_w, const float* bnb_w, const float* bnrm_w,
    const float* bnrv_w, const float* g2w_w, const float* fns_w, const float* fnm_w)
{
  int br = blockIdx.x >> 4, b = blockIdx.x & 15;
  const float* g1w  = br ? g1w_w  : g1w_h;
  const float* bng  = br ? bng_w  : bng_h;
  const float* bnb  = br ? bnb_w  : bnb_h;
  const float* bnrm = br ? bnrm_w : bnrm_h;
  const float* bnrv = br ? bnrv_w : bnrv_h;
  const float* g2w  = br ? g2w_w  : g2w_h;
  const float* fns  = br ? fns_w  : fns_h;
  const float* fnm  = br ? fnm_w  : fnm_h;

  __shared__ float gs[256][34];   // padded: col 0 and 33 are zero
  __shared__ float h1[64][34];
  __shared__ float red[8];
  int tid = threadIdx.x;
  const float* gb = g + (size_t)(br*BB + b) * 8192;

  gs[tid][0] = 0.f; gs[tid][33] = 0.f;
  if (tid < 64) { h1[tid][0] = 0.f; h1[tid][33] = 0.f; }
  #pragma unroll
  for (int it = 0; it < 32; ++it) {
    int idx = it*256 + tid;
    gs[idx >> 5][1 + (idx & 31)] = gb[idx];
  }
  __syncthreads();

  // conv1: thread -> (r = tid>>2, 8 l-values)
  {
    int r = tid >> 2, l0 = (tid & 3) * 8;
    float acc[8];
    #pragma unroll
    for (int j = 0; j < 8; ++j) acc[j] = 0.f;
    for (int c = 0; c < 256; ++c) {
      const float* wp = g1w + (r*256 + c)*3;
      float w0 = wp[0], w1 = wp[1], w2 = wp[2];
      float gv[10];
      #pragma unroll
      for (int q = 0; q < 10; ++q) gv[q] = gs[c][l0 + q];
      #pragma unroll
      for (int j = 0; j < 8; ++j) acc[j] += w0*gv[j] + w1*gv[j+1] + w2*gv[j+2];
    }
    float sc = bng[r] * rsqrtf(bnrv[r] + 1e-5f);
    float sh = bnb[r] - bnrm[r] * sc;
    #pragma unroll
    for (int j = 0; j < 8; ++j) {
      float v2 = acc[j]*sc + sh;                                    // BN
      float hs = v2 * fminf(fmaxf(v2 + 3.f, 0.f), 6.f) * (1.f/6.f); // hardswish
      h1[r][1 + l0 + j] = hs;
    }
  }
  __syncthreads();

  // conv2: thread -> one output channel c, all 32 l
  int c = tid;
  float a2[32];
  #pragma unroll
  for (int l = 0; l < 32; ++l) a2[l] = 0.f;
  for (int r = 0; r < 64; ++r) {
    const float* wp = g2w + (c*64 + r)*3;
    float w0 = wp[0], w1 = wp[1], w2 = wp[2];
    float hv[34];
    #pragma unroll
    for (int q = 0; q < 34; ++q) hv[q] = h1[r][q];
    #pragma unroll
    for (int l = 0; l < 32; ++l) a2[l] += w0*hv[l] + w1*hv[l+1] + w2*hv[l+2];
  }
  // per-batch mean/var over all (c,l)
  float s = 0.f, sq = 0.f;
  #pragma unroll
  for (int l = 0; l < 32; ++l) { s += a2[l]; sq += a2[l]*a2[l]; }
  #pragma unroll
  for (int off = 32; off >= 1; off >>= 1) { s += __shfl_xor(s, off); sq += __shfl_xor(sq, off); }
  int wid = tid >> 6;
  if ((tid & 63) == 0) { red[wid*2] = s; red[wid*2+1] = sq; }
  __syncthreads();
  float S  = red[0] + red[2] + red[4] + red[6];
  float SQ = red[1] + red[3] + red[5] + red[7];
  float u   = S * (1.f/8192.f);
  float var = SQ * (1.f/8192.f) - u*u;
  float inv = rsqrtf(var + 1e-6f);
  float* wo = wout + (size_t)(br*BB + b)*8192 + c*32;
  #pragma unroll
  for (int l = 0; l < 32; ++l)
    wo[l] = (a2[l] - u)*inv*fns[c*32 + l] + fnm[c*32 + l];
}

// ---------------------------------------------------------------------------
// K3: circulant apply per (b,ch). Writes ybr bf16 in (b,ch,h,w) layout.
__global__ __launch_bounds__(256) void k_circ(const float* __restrict__ x,
    const float* __restrict__ pe_h, const float* __restrict__ pe_w,
    const float* __restrict__ bias_h, const float* __restrict__ bias_w,
    const float* __restrict__ wgt, u16* __restrict__ ybr)
{
  int bc = blockIdx.x;
  int b = bc >> 9, ch = bc & 511, br = ch >> 8, c = ch & 255;
  __shared__ float xs[32][33];
  __shared__ float ww[32];
  int tid = threadIdx.x;
  const float* xp = x + (size_t)bc * 1024;
  float4 v = ((const float4*)xp)[tid];
  int h = tid >> 3, w4 = (tid & 7) * 4;
  if (br == 0) {
    float p = pe_h[c*32 + h];
    xs[h][w4+0] = v.x + p; xs[h][w4+1] = v.y + p;
    xs[h][w4+2] = v.z + p; xs[h][w4+3] = v.w + p;
  } else {
    xs[h][w4+0] = v.x + pe_w[c*32 + w4+0];
    xs[h][w4+1] = v.y + pe_w[c*32 + w4+1];
    xs[h][w4+2] = v.z + pe_w[c*32 + w4+2];
    xs[h][w4+3] = v.w + pe_w[c*32 + w4+3];
  }
  if (tid < 32) ww[tid] = wgt[((size_t)(br*BB + b)*256 + c)*32 + tid];
  __syncthreads();
  float bias = (br ? bias_w : bias_h)[c];
  int i = tid >> 3;
  float o0 = bias, o1 = bias, o2 = bias, o3 = bias;
  if (br == 0) {
    #pragma unroll
    for (int k = 0; k < 32; ++k) {
      float wk = ww[k]; int rr = (i + k) & 31;
      o0 += wk*xs[rr][w4+0]; o1 += wk*xs[rr][w4+1];
      o2 += wk*xs[rr][w4+2]; o3 += wk*xs[rr][w4+3];
    }
  } else {
    #pragma unroll
    for (int k = 0; k < 32; ++k) {
      float wk = ww[k];
      o0 += wk*xs[i][(w4+0+k) & 31]; o1 += wk*xs[i][(w4+1+k) & 31];
      o2 += wk*xs[i][(w4+2+k) & 31]; o3 += wk*xs[i][(w4+3+k) & 31];
    }
  }
  ushort4 o; o.x = f2bf(o0); o.y = f2bf(o1); o.z = f2bf(o2); o.w = f2bf(o3);
  ((ushort4*)(ybr + (size_t)bc * 1024))[tid] = o;
}

// ---------------------------------------------------------------------------
// K4: transpose (b,ch,h,w)->token-major + LayerNorm over 512 channels.
__global__ __launch_bounds__(256) void k_ln(const u16* __restrict__ ybr,
    const float* __restrict__ ln_w, const float* __restrict__ ln_b,
    u16* __restrict__ A)
{
  int bh = blockIdx.x; int b = bh >> 5, h = bh & 31;
  __shared__ float ys[512][33];
  __shared__ float ps[8][32], pq[8][32];
  __shared__ float mus[32], rstds[32];
  __shared__ float lw[512], lb[512];
  int tid = threadIdx.x;
  lw[tid]       = ln_w[tid];       lb[tid]       = ln_b[tid];
  lw[tid + 256] = ln_w[tid + 256]; lb[tid + 256] = ln_b[tid + 256];
  #pragma unroll
  for (int it = 0; it < 16; ++it) {
    int vid = it*256 + tid; int ch = vid >> 3; int w4 = (vid & 7) * 4;
    ushort4 v = *(const ushort4*)(ybr + (size_t)(b*512 + ch)*1024 + h*32 + w4);
    ys[ch][w4+0] = bf2f(v.x); ys[ch][w4+1] = bf2f(v.y);
    ys[ch][w4+2] = bf2f(v.z); ys[ch][w4+3] = bf2f(v.w);
  }
  __syncthreads();
  int w = tid & 31, gq = tid >> 5;
  float s = 0.f, sq = 0.f;
  for (int cc = gq*64; cc < gq*64 + 64; ++cc) { float vv = ys[cc][w]; s += vv; sq += vv*vv; }
  ps[gq][w] = s; pq[gq][w] = sq;
  __syncthreads();
  if (tid < 32) {
    float S = 0.f, SQ = 0.f;
    #pragma unroll
    for (int q = 0; q < 8; ++q) { S += ps[q][tid]; SQ += pq[q][tid]; }
    float mu = S * (1.f/512.f);
    float var = SQ * (1.f/512.f) - mu*mu;
    mus[tid] = mu; rstds[tid] = rsqrtf(var + 1e-6f);
  }
  __syncthreads();
  u16* Arow = A + (size_t)(b*1024 + h*32) * 512;
  #pragma unroll
  for (int it = 0; it < 64; ++it) {
    int idx = it*256 + tid; int w2 = idx >> 9, cc = idx & 511;
    float val = (ys[cc][w2] - mus[w2]) * rstds[w2] * lw[cc] + lb[cc];
    Arow[(size_t)w2*512 + cc] = f2bf(val);
  }
}

// ---------------------------------------------------------------------------
// K5/K6: MFMA GEMM, 128x128 tile, BK=64, 4 waves, 16x16x32 bf16.
// Round-4 proven skeleton (2 barriers/K-tile, per-wave counted vmcnt before
// the collective barrier) upgraded to DEPTH-2 prefetch with 3 LDS slots:
//   iter t: stage(t+2 -> slot (t+2)%3); vmcnt(16); barrier; compute slot t%3;
//   barrier.   Cover = 2 full compute iterations (~HBM latency).
// XCD-aware bijective block swizzle (nwg % 8 == 0 guaranteed by launch).
// LDS: linear dest for gload_lds, XOR-involution chunk swizzle (c^(r&7))
// applied to BOTH global source and read addresses (verified 0 conflicts).
// EPI=1: Z = gelu_approx(A@B + bias) bf16. EPI=2: residual fp32 out.
template<int EPI>
__global__ __launch_bounds__(256) void k_gemm(
    const u16* __restrict__ A, const u16* __restrict__ BT,
    void* __restrict__ outv, const float* __restrict__ xin,
    const float* __restrict__ bias, const float* __restrict__ gamma,
    int K, int N, int a_row_off, int out_row_off)
{
  __shared__ u16 As[3][8192];
  __shared__ u16 Bs[3][8192];
  int tid = threadIdx.x;
  // T1: XCD-aware bijective swizzle of the linear block id
  int nwgx = gridDim.x;
  int nwg  = nwgx * gridDim.y;
  int lin  = blockIdx.x + nwgx * blockIdx.y;
  int cpx  = nwg >> 3;
  int work = (lin & 7) * cpx + (lin >> 3);
  int m0 = (work % nwgx) * 128, n0 = (work / nwgx) * 128;

  int lane = tid & 63, wid = tid >> 6;
  int wr = wid >> 1, wc = wid & 1;
  f32x4 acc[4][4];
  #pragma unroll
  for (int mi = 0; mi < 4; ++mi)
    #pragma unroll
    for (int ni = 0; ni < 4; ++ni) acc[mi][ni] = (f32x4){0.f,0.f,0.f,0.f};

  // staging: 1024 chunks of 16B per tile. LDS chunk q (linear) holds
  // logical (row = q>>3, colchunk = (q&7) ^ ((q>>3)&7)).
  const u16* Ag[4]; const u16* Bg[4]; int cbs[4];
  #pragma unroll
  for (int i = 0; i < 4; ++i) {
    int cb = (wid*4 + i) * 64;          // wave-uniform chunk base
    int q  = cb + lane;
    int r  = q >> 3, ccs = (q & 7) ^ (r & 7);   // pre-swizzled source chunk
    Ag[i] = A  + (size_t)(a_row_off + m0 + r)*K + ccs*8;
    Bg[i] = BT + (size_t)(n0 + r)*K + ccs*8;
    cbs[i] = cb*8;                      // u16 index of wave-uniform LDS base
  }

  auto stage = [&](int t, int slot) {
    int k0 = t << 6;
    #pragma unroll
    for (int i = 0; i < 4; ++i) {
      gload16(Ag[i] + k0, &As[slot][cbs[i]]);
      gload16(Bg[i] + k0, &Bs[slot][cbs[i]]);
    }
  };

  int nt = K >> 6;
  // prologue: depth-2 prefetch
  stage(0, 0);
  if (nt > 1) stage(1, 1);

  for (int t = 0; t < nt; ++t) {
    int slot = t % 3;
    if (t + 2 < nt) {
      stage(t + 2, (t + 2) % 3);
      asm volatile("s_waitcnt vmcnt(16)" ::: "memory");  // tile t landed; t+1,t+2 in flight
    } else if (t + 1 < nt) {
      asm volatile("s_waitcnt vmcnt(8)" ::: "memory");   // tile t landed; t+1 in flight
    } else {
      asm volatile("s_waitcnt vmcnt(0)" ::: "memory");
    }
    __builtin_amdgcn_s_barrier();                        // tile t collectively valid
    const u16* Ar = &As[slot][0];
    const u16* Br = &Bs[slot][0];
    #pragma unroll
    for (int kk = 0; kk < 64; kk += 32) {
      bf16x8 af[4], bfr[4];
      #pragma unroll
      for (int mi = 0; mi < 4; ++mi) {
        int row = wr*64 + mi*16 + (lane & 15);
        int j = (kk >> 3) + (lane >> 4);            // logical colchunk 0..7
        af[mi] = *(const bf16x8*)&Ar[row*64 + ((j ^ (row & 7)) << 3)];
      }
      #pragma unroll
      for (int ni = 0; ni < 4; ++ni) {
        int row = wc*64 + ni*16 + (lane & 15);
        int j = (kk >> 3) + (lane >> 4);
        bfr[ni] = *(const bf16x8*)&Bs[slot][row*64 + ((j ^ (row & 7)) << 3)];
      }
      #pragma unroll
      for (int mi = 0; mi < 4; ++mi)
        #pragma unroll
        for (int ni = 0; ni < 4; ++ni)
          acc[mi][ni] = __builtin_amdgcn_mfma_f32_16x16x32_bf16(af[mi], bfr[ni], acc[mi][ni], 0, 0, 0);
    }
    __builtin_amdgcn_s_barrier();   // protect slot (t-1)%3 target of next stage
  }

  // epilogue: D layout col = lane&15, row = (lane>>4)*4 + reg
  #pragma unroll
  for (int mi = 0; mi < 4; ++mi) {
    #pragma unroll
    for (int ni = 0; ni < 4; ++ni) {
      int n = n0 + wc*64 + ni*16 + (lane & 15);
      float bn = bias[n];
      #pragma unroll
      for (int r = 0; r < 4; ++r) {
        int m = m0 + wr*64 + mi*16 + (lane >> 4)*4 + r;
        float v = acc[mi][ni][r] + bn;
        if (EPI == 1) {
          float ge = v / (1.f + __expf(-1.702f * v));   // sigmoid-approx GELU
          ((u16*)outv)[(size_t)m*N + n] = f2bf(ge);
        } else {
          float yv = gamma[n] * v;
          int mg = out_row_off + m;
          int bb = mg >> 10, hh = (mg >> 5) & 31, wv = mg & 31;
          size_t oi = ((size_t)(bb*512 + n))*1024 + hh*32 + wv;
          ((float*)outv)[oi] = xin[oi] + yv;
        }
      }
    }
  }
}

// ---------------------------------------------------------------------------
extern "C" void kernel_launch(void* const* d_in, const int* in_sizes, int n_in,
                              void* d_out, int out_size, void* d_ws, size_t ws_size,
                              hipStream_t stream)
{
  const float* x      = (const float*)d_in[0];
  const float* pe_h   = (const float*)d_in[1];
  const float* g1w_h  = (const float*)d_in[2];
  const float* bng_h  = (const float*)d_in[3];
  const float* bnb_h  = (const float*)d_in[4];
  const float* bnrm_h = (const float*)d_in[5];
  const float* bnrv_h = (const float*)d_in[6];
  const float* g2w_h  = (const float*)d_in[7];
  const float* fns_h  = (const float*)d_in[8];
  const float* fnm_h  = (const float*)d_in[9];
  const float* bias_h = (const float*)d_in[10];
  const float* pe_w   = (const float*)d_in[11];
  const float* g1w_w  = (const float*)d_in[12];
  const float* bng_w  = (const float*)d_in[13];
  const float* bnb_w  = (const float*)d_in[14];
  const float* bnrm_w = (const float*)d_in[15];
  const float* bnrv_w = (const float*)d_in[16];
  const float* g2w_w  = (const float*)d_in[17];
  const float* fns_w  = (const float*)d_in[18];
  const float* fnm_w  = (const float*)d_in[19];
  const float* bias_w = (const float*)d_in[20];
  const float* ln_w   = (const float*)d_in[21];
  const float* ln_b   = (const float*)d_in[22];
  const float* pw1w   = (const float*)d_in[23];
  const float* pw1b   = (const float*)d_in[24];
  const float* pw2w   = (const float*)d_in[25];
  const float* pw2b   = (const float*)d_in[26];
  const float* gamma  = (const float*)d_in[27];
  float* out = (float*)d_out;

  char* ws = (char*)d_ws;
  size_t off = 0;
  auto carve = [&](size_t bytes) -> void* {
    void* p = ws + off; off += (bytes + 255) & ~(size_t)255; return p;
  };
  float* g   = (float*)carve((size_t)2*BB*256*32*4);   // 1 MB
  float* wgt = (float*)carve((size_t)2*BB*256*32*4);   // 1 MB
  u16* BT1   = (u16*)carve((size_t)2048*512*2);        // 2 MB
  u16* BT2   = (u16*)carve((size_t)512*2048*2);        // 2 MB
  u16* Abuf  = (u16*)carve((size_t)NTOK*512*2);        // 16.8 MB
  size_t tail = off;                                   // ybr / Z share this region
  u16* ybr = (u16*)(ws + tail);
  u16* Z   = (u16*)(ws + tail);                        // Z overwrites dead ybr
  size_t ybr_bytes = (size_t)NTOK*512*2;               // 16.8 MB
  int nch = 1;                                         // chunk M so Z fits in ws
  while (nch < 16) {
    size_t zb = ((size_t)NTOK/nch)*2048*2;
    size_t need = tail + (zb > ybr_bytes ? zb : ybr_bytes);
    if (need <= ws_size) break;
    nch *= 2;
  }

  k_pre<<<512 + BB*512, 256, 0, stream>>>(pw1w, BT1, pw2w, BT2, x, pe_h, pe_w, g);
  k_gen<<<32, 256, 0, stream>>>(g, wgt,
      g1w_h, bng_h, bnb_h, bnrm_h, bnrv_h, g2w_h, fns_h, fnm_h,
      g1w_w, bng_w, bnb_w, bnrm_w, bnrv_w, g2w_w, fns_w, fnm_w);
  k_circ<<<BB*512, 256, 0, stream>>>(x, pe_h, pe_w, bias_h, bias_w, wgt, ybr);
  k_ln<<<BB*LL, 256, 0, stream>>>(ybr, ln_w, ln_b, Abuf);

  int Mc = NTOK / nch;
  for (int ci = 0; ci < nch; ++ci) {
    int moff = ci * Mc;
    k_gemm<1><<<dim3(Mc/128, 2048/128), 256, 0, stream>>>(
        Abuf, BT1, Z, nullptr, pw1b, nullptr, 512, 2048, moff, 0);
    k_gemm<2><<<dim3(Mc/128, 512/128), 256, 0, stream>>>(
        Z, BT2, out, x, pw2b, gamma, 2048, 512, 0, moff);
  }
}

// Round 7
// 207.121 us; speedup vs baseline: 1.3325x; 1.3325x over previous
//
#include <hip/hip_runtime.h>
#include <stdint.h>

// Problem constants
#define BB    16
#define DIMC  512
#define CHC   256
#define REDC  64
#define LL    32          // H == W == 32
#define NTOK  (BB*LL*LL)  // 16384 tokens

typedef unsigned short u16;
typedef __attribute__((ext_vector_type(4))) float f32x4;
typedef __attribute__((ext_vector_type(8))) short bf16x8;

__device__ __forceinline__ float bf2f(u16 u){
  union { unsigned int i; float f; } v; v.i = ((unsigned int)u) << 16; return v.f;
}
__device__ __forceinline__ u16 f2bf(float f){
  union { float f; unsigned int i; } v; v.f = f;
  unsigned int r = (v.i + 0x7FFFu + ((v.i >> 16) & 1u)) >> 16;
  return (u16)r;
}

// async global->LDS, 16B per lane; LDS base must be wave-uniform.
__device__ __forceinline__ void gload16(const u16* g, u16* l) {
  __builtin_amdgcn_global_load_lds(
      (const __attribute__((address_space(1))) void*)g,
      (__attribute__((address_space(3))) void*)l, 16, 0, 0);
}

// ---------------------------------------------------------------------------
// K0: fused pre-pass. Blocks 0..511: weight transposes fp32 [K][N]->bf16 [N][K].
// Blocks 512..8703: per-(b,ch) axis means -> g[br][b][c][l].
__global__ __launch_bounds__(256) void k_pre(const float* __restrict__ s1,
    u16* __restrict__ d1, const float* __restrict__ s2, u16* __restrict__ d2,
    const float* __restrict__ x, const float* __restrict__ pe_h,
    const float* __restrict__ pe_w, float* __restrict__ g)
{
  int tid = threadIdx.x;
  if (blockIdx.x < 512) {
    __shared__ u16 t[64][65];
    int bid = blockIdx.x;
    const float* src; u16* dst; int K, N, n0, k0;
    if (bid < 256) { src = s1; dst = d1; K = 512;  N = 2048; n0 = (bid & 31) * 64; k0 = (bid >> 5) * 64; }
    else { bid -= 256; src = s2; dst = d2; K = 2048; N = 512; n0 = (bid & 7) * 64; k0 = (bid >> 3) * 64; }
    #pragma unroll
    for (int i = 0; i < 16; ++i) {
      int idx = i*256 + tid; int r = idx >> 6, c = idx & 63;
      t[r][c] = f2bf(src[(size_t)(k0 + r) * N + n0 + c]);
    }
    __syncthreads();
    #pragma unroll
    for (int i = 0; i < 16; ++i) {
      int idx = i*256 + tid; int c = idx >> 6, r = idx & 63;
      dst[(size_t)(n0 + c) * K + k0 + r] = t[r][c];
    }
    return;
  }
  // ---- means part ----
  int bc = blockIdx.x - 512;           // b*512 + ch
  int br = (bc & 511) >> 8, c = bc & 255;
  __shared__ float tt[32][33];
  const float* xp = x + (size_t)bc * 1024;
  float4 v = ((const float4*)xp)[tid];
  int h = tid >> 3, w4 = (tid & 7) * 4;
  tt[h][w4+0] = v.x; tt[h][w4+1] = v.y; tt[h][w4+2] = v.z; tt[h][w4+3] = v.w;
  __syncthreads();
  if (tid < 32) {
    float rs = 0.f;
    if (br == 0) {
      #pragma unroll
      for (int w = 0; w < 32; ++w) rs += tt[tid][w];     // mean over W (H-branch)
    } else {
      #pragma unroll
      for (int h2 = 0; h2 < 32; ++h2) rs += tt[h2][tid]; // mean over H (W-branch)
    }
    float tot = rs;
    #pragma unroll
    for (int off = 16; off >= 1; off >>= 1) tot += __shfl_xor(tot, off);
    const float* pe = (br == 0 ? pe_h : pe_w) + c*32;
    float pv = pe[tid];
    float pm = pv;
    #pragma unroll
    for (int off = 16; off >= 1; off >>= 1) pm += __shfl_xor(pm, off);
    int b = bc >> 9;
    float gv = rs * (1.f/32.f) + tot * (1.f/1024.f) + pv + pm * (1.f/32.f);
    g[((size_t)(br*BB + b)*256 + c)*32 + tid] = gv;
  }
}

// ---------------------------------------------------------------------------
// K2: generator net: conv1(256->64,k3) -> BN -> hardswish -> conv2(64->256,k3)
//     -> per-batch filter norm * fns + fnm.  One block per (branch, batch).
__global__ __launch_bounds__(256) void k_gen(
    const float* __restrict__ g, float* __restrict__ wout,
    const float* g1w_h, const float* bng_h, const float* bnb_h, const float* bnrm_h,
    const float* bnrv_h, const float* g2w_h, const float* fns_h, const float* fnm_h,
    const float* g1w_w, const float* bng_w, const float* bnb_w, const float* bnrm_w,
    const float* bnrv_w, const float* g2w_w, const float* fns_w, const float* fnm_w)
{
  int br = blockIdx.x >> 4, b = blockIdx.x & 15;
  const float* g1w  = br ? g1w_w  : g1w_h;
  const float* bng  = br ? bng_w  : bng_h;
  const float* bnb  = br ? bnb_w  : bnb_h;
  const float* bnrm = br ? bnrm_w : bnrm_h;
  const float* bnrv = br ? bnrv_w : bnrv_h;
  const float* g2w  = br ? g2w_w  : g2w_h;
  const float* fns  = br ? fns_w  : fns_h;
  const float* fnm  = br ? fnm_w  : fnm_h;

  __shared__ float gs[256][34];   // padded: col 0 and 33 are zero
  __shared__ float h1[64][34];
  __shared__ float red[8];
  int tid = threadIdx.x;
  const float* gb = g + (size_t)(br*BB + b) * 8192;

  gs[tid][0] = 0.f; gs[tid][33] = 0.f;
  if (tid < 64) { h1[tid][0] = 0.f; h1[tid][33] = 0.f; }
  #pragma unroll
  for (int it = 0; it < 32; ++it) {
    int idx = it*256 + tid;
    gs[idx >> 5][1 + (idx & 31)] = gb[idx];
  }
  __syncthreads();

  // conv1: thread -> (r = tid>>2, 8 l-values)
  {
    int r = tid >> 2, l0 = (tid & 3) * 8;
    float acc[8];
    #pragma unroll
    for (int j = 0; j < 8; ++j) acc[j] = 0.f;
    for (int c = 0; c < 256; ++c) {
      const float* wp = g1w + (r*256 + c)*3;
      float w0 = wp[0], w1 = wp[1], w2 = wp[2];
      float gv[10];
      #pragma unroll
      for (int q = 0; q < 10; ++q) gv[q] = gs[c][l0 + q];
      #pragma unroll
      for (int j = 0; j < 8; ++j) acc[j] += w0*gv[j] + w1*gv[j+1] + w2*gv[j+2];
    }
    float sc = bng[r] * rsqrtf(bnrv[r] + 1e-5f);
    float sh = bnb[r] - bnrm[r] * sc;
    #pragma unroll
    for (int j = 0; j < 8; ++j) {
      float v2 = acc[j]*sc + sh;                                    // BN
      float hs = v2 * fminf(fmaxf(v2 + 3.f, 0.f), 6.f) * (1.f/6.f); // hardswish
      h1[r][1 + l0 + j] = hs;
    }
  }
  __syncthreads();

  // conv2: thread -> one output channel c, all 32 l
  int c = tid;
  float a2[32];
  #pragma unroll
  for (int l = 0; l < 32; ++l) a2[l] = 0.f;
  for (int r = 0; r < 64; ++r) {
    const float* wp = g2w + (c*64 + r)*3;
    float w0 = wp[0], w1 = wp[1], w2 = wp[2];
    float hv[34];
    #pragma unroll
    for (int q = 0; q < 34; ++q) hv[q] = h1[r][q];
    #pragma unroll
    for (int l = 0; l < 32; ++l) a2[l] += w0*hv[l] + w1*hv[l+1] + w2*hv[l+2];
  }
  // per-batch mean/var over all (c,l)
  float s = 0.f, sq = 0.f;
  #pragma unroll
  for (int l = 0; l < 32; ++l) { s += a2[l]; sq += a2[l]*a2[l]; }
  #pragma unroll
  for (int off = 32; off >= 1; off >>= 1) { s += __shfl_xor(s, off); sq += __shfl_xor(sq, off); }
  int wid = tid >> 6;
  if ((tid & 63) == 0) { red[wid*2] = s; red[wid*2+1] = sq; }
  __syncthreads();
  float S  = red[0] + red[2] + red[4] + red[6];
  float SQ = red[1] + red[3] + red[5] + red[7];
  float u   = S * (1.f/8192.f);
  float var = SQ * (1.f/8192.f) - u*u;
  float inv = rsqrtf(var + 1e-6f);
  float* wo = wout + (size_t)(br*BB + b)*8192 + c*32;
  #pragma unroll
  for (int l = 0; l < 32; ++l)
    wo[l] = (a2[l] - u)*inv*fns[c*32 + l] + fnm[c*32 + l];
}

// ---------------------------------------------------------------------------
// K3: circulant apply per (b,ch). Writes ybr bf16 in (b,ch,h,w) layout.
__global__ __launch_bounds__(256) void k_circ(const float* __restrict__ x,
    const float* __restrict__ pe_h, const float* __restrict__ pe_w,
    const float* __restrict__ bias_h, const float* __restrict__ bias_w,
    const float* __restrict__ wgt, u16* __restrict__ ybr)
{
  int bc = blockIdx.x;
  int b = bc >> 9, ch = bc & 511, br = ch >> 8, c = ch & 255;
  __shared__ float xs[32][33];
  __shared__ float ww[32];
  int tid = threadIdx.x;
  const float* xp = x + (size_t)bc * 1024;
  float4 v = ((const float4*)xp)[tid];
  int h = tid >> 3, w4 = (tid & 7) * 4;
  if (br == 0) {
    float p = pe_h[c*32 + h];
    xs[h][w4+0] = v.x + p; xs[h][w4+1] = v.y + p;
    xs[h][w4+2] = v.z + p; xs[h][w4+3] = v.w + p;
  } else {
    xs[h][w4+0] = v.x + pe_w[c*32 + w4+0];
    xs[h][w4+1] = v.y + pe_w[c*32 + w4+1];
    xs[h][w4+2] = v.z + pe_w[c*32 + w4+2];
    xs[h][w4+3] = v.w + pe_w[c*32 + w4+3];
  }
  if (tid < 32) ww[tid] = wgt[((size_t)(br*BB + b)*256 + c)*32 + tid];
  __syncthreads();
  float bias = (br ? bias_w : bias_h)[c];
  int i = tid >> 3;
  float o0 = bias, o1 = bias, o2 = bias, o3 = bias;
  if (br == 0) {
    #pragma unroll
    for (int k = 0; k < 32; ++k) {
      float wk = ww[k]; int rr = (i + k) & 31;
      o0 += wk*xs[rr][w4+0]; o1 += wk*xs[rr][w4+1];
      o2 += wk*xs[rr][w4+2]; o3 += wk*xs[rr][w4+3];
    }
  } else {
    #pragma unroll
    for (int k = 0; k < 32; ++k) {
      float wk = ww[k];
      o0 += wk*xs[i][(w4+0+k) & 31]; o1 += wk*xs[i][(w4+1+k) & 31];
      o2 += wk*xs[i][(w4+2+k) & 31]; o3 += wk*xs[i][(w4+3+k) & 31];
    }
  }
  ushort4 o; o.x = f2bf(o0); o.y = f2bf(o1); o.z = f2bf(o2); o.w = f2bf(o3);
  ((ushort4*)(ybr + (size_t)bc * 1024))[tid] = o;
}

// ---------------------------------------------------------------------------
// K4: transpose (b,ch,h,w)->token-major + LayerNorm over 512 channels.
__global__ __launch_bounds__(256) void k_ln(const u16* __restrict__ ybr,
    const float* __restrict__ ln_w, const float* __restrict__ ln_b,
    u16* __restrict__ A)
{
  int bh = blockIdx.x; int b = bh >> 5, h = bh & 31;
  __shared__ float ys[512][33];
  __shared__ float ps[8][32], pq[8][32];
  __shared__ float mus[32], rstds[32];
  __shared__ float lw[512], lb[512];
  int tid = threadIdx.x;
  lw[tid]       = ln_w[tid];       lb[tid]       = ln_b[tid];
  lw[tid + 256] = ln_w[tid + 256]; lb[tid + 256] = ln_b[tid + 256];
  #pragma unroll
  for (int it = 0; it < 16; ++it) {
    int vid = it*256 + tid; int ch = vid >> 3; int w4 = (vid & 7) * 4;
    ushort4 v = *(const ushort4*)(ybr + (size_t)(b*512 + ch)*1024 + h*32 + w4);
    ys[ch][w4+0] = bf2f(v.x); ys[ch][w4+1] = bf2f(v.y);
    ys[ch][w4+2] = bf2f(v.z); ys[ch][w4+3] = bf2f(v.w);
  }
  __syncthreads();
  int w = tid & 31, gq = tid >> 5;
  float s = 0.f, sq = 0.f;
  for (int cc = gq*64; cc < gq*64 + 64; ++cc) { float vv = ys[cc][w]; s += vv; sq += vv*vv; }
  ps[gq][w] = s; pq[gq][w] = sq;
  __syncthreads();
  if (tid < 32) {
    float S = 0.f, SQ = 0.f;
    #pragma unroll
    for (int q = 0; q < 8; ++q) { S += ps[q][tid]; SQ += pq[q][tid]; }
    float mu = S * (1.f/512.f);
    float var = SQ * (1.f/512.f) - mu*mu;
    mus[tid] = mu; rstds[tid] = rsqrtf(var + 1e-6f);
  }
  __syncthreads();
  u16* Arow = A + (size_t)(b*1024 + h*32) * 512;
  #pragma unroll
  for (int it = 0; it < 64; ++it) {
    int idx = it*256 + tid; int w2 = idx >> 9, cc = idx & 511;
    float val = (ys[cc][w2] - mus[w2]) * rstds[w2] * lw[cc] + lb[cc];
    Arow[(size_t)w2*512 + cc] = f2bf(val);
  }
}

// ---------------------------------------------------------------------------
// K5/K6: MFMA GEMM, 128x128 tile, BK=64, **8 waves / 512 threads**,
// 16x16x32 bf16. Round-4 proven pipeline: 2-slot LDS double-buffer,
// stage(t+1) -> per-wave counted s_waitcnt vmcnt(4) -> raw s_barrier ->
// ds_read+MFMA -> raw s_barrier. Each wave: 32x64 output (2x4 frags),
// 4 gload_lds per K-tile -> steady-state vmcnt(4).
// LDS: linear dest for gload_lds, XOR-involution chunk swizzle (c^(r&7))
// applied to BOTH global source and read addresses (verified 0 conflicts).
// 64KB LDS + <=128 VGPR -> 2 blocks/CU = 4 waves/SIMD (vs round-4's 2).
// EPI=1: Z = gelu_approx(A@B + bias) bf16. EPI=2: residual fp32 out.
template<int EPI>
__global__ __launch_bounds__(512, 4) void k_gemm(
    const u16* __restrict__ A, const u16* __restrict__ BT,
    void* __restrict__ outv, const float* __restrict__ xin,
    const float* __restrict__ bias, const float* __restrict__ gamma,
    int K, int N, int a_row_off, int out_row_off)
{
  __shared__ u16 As[2][8192];
  __shared__ u16 Bs[2][8192];
  int tid = threadIdx.x;
  int m0 = blockIdx.x * 128, n0 = blockIdx.y * 128;
  int lane = tid & 63, wid = tid >> 6;
  int wr = wid >> 1, wc = wid & 1;          // wave tile: rows wr*32.., cols wc*64..
  f32x4 acc[2][4];
  #pragma unroll
  for (int mi = 0; mi < 2; ++mi)
    #pragma unroll
    for (int ni = 0; ni < 4; ++ni) acc[mi][ni] = (f32x4){0.f,0.f,0.f,0.f};

  // staging: 1024 chunks of 16B per tile. LDS chunk q (linear) holds
  // logical (row = q>>3, colchunk = (q&7) ^ ((q>>3)&7)).
  // Wave w, piece i (i=0,1): chunks [w*128 + i*64, +64).
  const u16* Ag[2]; const u16* Bg[2]; int cbs[2];
  #pragma unroll
  for (int i = 0; i < 2; ++i) {
    int cb = wid*128 + i*64;            // wave-uniform chunk base
    int q  = cb + lane;
    int r  = q >> 3, ccs = (q & 7) ^ (r & 7);   // pre-swizzled source chunk
    Ag[i] = A  + (size_t)(a_row_off + m0 + r)*K + ccs*8;
    Bg[i] = BT + (size_t)(n0 + r)*K + ccs*8;
    cbs[i] = cb*8;                      // u16 index of wave-uniform LDS base
  }

  auto stage = [&](int t, int slot) {
    int k0 = t << 6;
    #pragma unroll
    for (int i = 0; i < 2; ++i) {
      gload16(Ag[i] + k0, &As[slot][cbs[i]]);
      gload16(Bg[i] + k0, &Bs[slot][cbs[i]]);
    }
  };

  int nt = K >> 6;
  stage(0, 0);                          // prologue

  for (int t = 0; t < nt; ++t) {
    int cur = t & 1;
    if (t + 1 < nt) {
      stage(t + 1, cur ^ 1);
      asm volatile("s_waitcnt vmcnt(4)" ::: "memory");   // tile-t loads landed
    } else {
      asm volatile("s_waitcnt vmcnt(0)" ::: "memory");
    }
    __builtin_amdgcn_s_barrier();                        // tile t collectively valid
    const u16* Ar = &As[cur][0];
    const u16* Br = &Bs[cur][0];
    #pragma unroll
    for (int kk = 0; kk < 64; kk += 32) {
      bf16x8 af[2], bfr[4];
      #pragma unroll
      for (int mi = 0; mi < 2; ++mi) {
        int row = wr*32 + mi*16 + (lane & 15);
        int j = (kk >> 3) + (lane >> 4);            // logical colchunk 0..7
        af[mi] = *(const bf16x8*)&Ar[row*64 + ((j ^ (row & 7)) << 3)];
      }
      #pragma unroll
      for (int ni = 0; ni < 4; ++ni) {
        int row = wc*64 + ni*16 + (lane & 15);
        int j = (kk >> 3) + (lane >> 4);
        bfr[ni] = *(const bf16x8*)&Br[row*64 + ((j ^ (row & 7)) << 3)];
      }
      #pragma unroll
      for (int mi = 0; mi < 2; ++mi)
        #pragma unroll
        for (int ni = 0; ni < 4; ++ni)
          acc[mi][ni] = __builtin_amdgcn_mfma_f32_16x16x32_bf16(af[mi], bfr[ni], acc[mi][ni], 0, 0, 0);
    }
    __builtin_amdgcn_s_barrier();   // protect the slot the next stage overwrites
  }

  // epilogue: D layout col = lane&15, row = (lane>>4)*4 + reg
  #pragma unroll
  for (int mi = 0; mi < 2; ++mi) {
    #pragma unroll
    for (int ni = 0; ni < 4; ++ni) {
      int n = n0 + wc*64 + ni*16 + (lane & 15);
      float bn = bias[n];
      #pragma unroll
      for (int r = 0; r < 4; ++r) {
        int m = m0 + wr*32 + mi*16 + (lane >> 4)*4 + r;
        float v = acc[mi][ni][r] + bn;
        if (EPI == 1) {
          float ge = v / (1.f + __expf(-1.702f * v));   // sigmoid-approx GELU
          ((u16*)outv)[(size_t)m*N + n] = f2bf(ge);
        } else {
          float yv = gamma[n] * v;
          int mg = out_row_off + m;
          int bb = mg >> 10, hh = (mg >> 5) & 31, wv = mg & 31;
          size_t oi = ((size_t)(bb*512 + n))*1024 + hh*32 + wv;
          ((float*)outv)[oi] = xin[oi] + yv;
        }
      }
    }
  }
}

// ---------------------------------------------------------------------------
extern "C" void kernel_launch(void* const* d_in, const int* in_sizes, int n_in,
                              void* d_out, int out_size, void* d_ws, size_t ws_size,
                              hipStream_t stream)
{
  const float* x      = (const float*)d_in[0];
  const float* pe_h   = (const float*)d_in[1];
  const float* g1w_h  = (const float*)d_in[2];
  const float* bng_h  = (const float*)d_in[3];
  const float* bnb_h  = (const float*)d_in[4];
  const float* bnrm_h = (const float*)d_in[5];
  const float* bnrv_h = (const float*)d_in[6];
  const float* g2w_h  = (const float*)d_in[7];
  const float* fns_h  = (const float*)d_in[8];
  const float* fnm_h  = (const float*)d_in[9];
  const float* bias_h = (const float*)d_in[10];
  const float* pe_w   = (const float*)d_in[11];
  const float* g1w_w  = (const float*)d_in[12];
  const float* bng_w  = (const float*)d_in[13];
  const float* bnb_w  = (const float*)d_in[14];
  const float* bnrm_w = (const float*)d_in[15];
  const float* bnrv_w = (const float*)d_in[16];
  const float* g2w_w  = (const float*)d_in[17];
  const float* fns_w  = (const float*)d_in[18];
  const float* fnm_w  = (const float*)d_in[19];
  const float* bias_w = (const float*)d_in[20];
  const float* ln_w   = (const float*)d_in[21];
  const float* ln_b   = (const float*)d_in[22];
  const float* pw1w   = (const float*)d_in[23];
  const float* pw1b   = (const float*)d_in[24];
  const float* pw2w   = (const float*)d_in[25];
  const float* pw2b   = (const float*)d_in[26];
  const float* gamma  = (const float*)d_in[27];
  float* out = (float*)d_out;

  char* ws = (char*)d_ws;
  size_t off = 0;
  auto carve = [&](size_t bytes) -> void* {
    void* p = ws + off; off += (bytes + 255) & ~(size_t)255; return p;
  };
  float* g   = (float*)carve((size_t)2*BB*256*32*4);   // 1 MB
  float* wgt = (float*)carve((size_t)2*BB*256*32*4);   // 1 MB
  u16* BT1   = (u16*)carve((size_t)2048*512*2);        // 2 MB
  u16* BT2   = (u16*)carve((size_t)512*2048*2);        // 2 MB
  u16* Abuf  = (u16*)carve((size_t)NTOK*512*2);        // 16.8 MB
  size_t tail = off;                                   // ybr / Z share this region
  u16* ybr = (u16*)(ws + tail);
  u16* Z   = (u16*)(ws + tail);                        // Z overwrites dead ybr
  size_t ybr_bytes = (size_t)NTOK*512*2;               // 16.8 MB
  int nch = 1;                                         // chunk M so Z fits in ws
  while (nch < 16) {
    size_t zb = ((size_t)NTOK/nch)*2048*2;
    size_t need = tail + (zb > ybr_bytes ? zb : ybr_bytes);
    if (need <= ws_size) break;
    nch *= 2;
  }

  k_pre<<<512 + BB*512, 256, 0, stream>>>(pw1w, BT1, pw2w, BT2, x, pe_h, pe_w, g);
  k_gen<<<32, 256, 0, stream>>>(g, wgt,
      g1w_h, bng_h, bnb_h, bnrm_h, bnrv_h, g2w_h, fns_h, fnm_h,
      g1w_w, bng_w, bnb_w, bnrm_w, bnrv_w, g2w_w, fns_w, fnm_w);
  k_circ<<<BB*512, 256, 0, stream>>>(x, pe_h, pe_w, bias_h, bias_w, wgt, ybr);
  k_ln<<<BB*LL, 256, 0, stream>>>(ybr, ln_w, ln_b, Abuf);

  int Mc = NTOK / nch;
  for (int ci = 0; ci < nch; ++ci) {
    int moff = ci * Mc;
    k_gemm<1><<<dim3(Mc/128, 2048/128), 512, 0, stream>>>(
        Abuf, BT1, Z, nullptr, pw1b, nullptr, 512, 2048, moff, 0);
    k_gemm<2><<<dim3(Mc/128, 512/128), 512, 0, stream>>>(
        Z, BT2, out, x, pw2b, gamma, 2048, 512, 0, moff);
  }
}